// Round 7
// baseline (159.290 us; speedup 1.0000x reference)
//
#include <hip/hip_runtime.h>
#include <cstdint>

#define MARGIN_F 0.2f

typedef __attribute__((ext_vector_type(8))) short sv8;   // 8 x bf16 (4 VGPRs)
typedef __attribute__((ext_vector_type(4))) float fv4;   // MFMA accumulator

// ---- round-to-nearest-even fp32 -> bf16 (bit pattern) ----
__device__ __forceinline__ unsigned short f2bf(float x) {
    unsigned u = __float_as_uint(x);
    unsigned r = (u + 0x7fffu + ((u >> 16) & 1u)) >> 16;
    return (unsigned short)r;
}

// =====================================================================
// prep: norms, d_pos (fp32 exact) + bf16 conversion of e1,e2
// =====================================================================
__global__ __launch_bounds__(128) void prep_kernel(
    const float* __restrict__ e1, const float* __restrict__ e2,
    unsigned short* __restrict__ e1b, unsigned short* __restrict__ e2b,
    float* __restrict__ n1, float* __restrict__ n2, float* __restrict__ dpos)
{
    const int row = blockIdx.x;
    const int t = threadIdx.x;
    const float4 a = reinterpret_cast<const float4*>(e1 + (size_t)row * 512)[t];
    const float4 b = reinterpret_cast<const float4*>(e2 + (size_t)row * 512)[t];

    ushort4 pa, pb;
    pa.x = f2bf(a.x); pa.y = f2bf(a.y); pa.z = f2bf(a.z); pa.w = f2bf(a.w);
    pb.x = f2bf(b.x); pb.y = f2bf(b.y); pb.z = f2bf(b.z); pb.w = f2bf(b.w);
    reinterpret_cast<ushort4*>(e1b + (size_t)row * 512)[t] = pa;
    reinterpret_cast<ushort4*>(e2b + (size_t)row * 512)[t] = pb;

    float s1 = a.x*a.x + a.y*a.y + a.z*a.z + a.w*a.w;
    float s2 = b.x*b.x + b.y*b.y + b.z*b.z + b.w*b.w;
    float dx = a.x-b.x, dy = a.y-b.y, dz = a.z-b.z, dw = a.w-b.w;
    float sp = dx*dx + dy*dy + dz*dz + dw*dw;

    #pragma unroll
    for (int o = 32; o; o >>= 1) {
        s1 += __shfl_down(s1, o);
        s2 += __shfl_down(s2, o);
        sp += __shfl_down(sp, o);
    }
    __shared__ float r1[2], r2[2], rp[2];
    if ((t & 63) == 0) { int wv = t >> 6; r1[wv] = s1; r2[wv] = s2; rp[wv] = sp; }
    __syncthreads();
    if (t == 0) {
        n1[row] = r1[0] + r1[1];
        n2[row] = r2[0] + r2[1];
        dpos[row] = sqrtf(rp[0] + rp[1]);
    }
}

// =====================================================================
// main: pair-block scheme over 64x64 tiles, (bi<=bj) triangle (R2-proven
// decomposition + emission), but NO LDS staging and NO barriers in the
// K-loop: each wave loads its MFMA fragments directly from global
// (L1/L2-resident; frag == one global_load_dwordx4 with k as a
// compile-time offset: immediate). XCD-chunked bid swizzle for L2 locality.
// grid: 2080 blocks x 256 threads (4 waves, 2x2; wave region 32x32)
// =====================================================================
__global__ __launch_bounds__(256, 3) void triplet_main(
    const unsigned short* __restrict__ e1b, const unsigned short* __restrict__ e2b,
    const float* __restrict__ n1, const float* __restrict__ n2,
    const float* __restrict__ dpos,
    float* __restrict__ total, unsigned* __restrict__ count)
{
    __shared__ float sc[384];          // [0:192) i-side, [192:384) j-side
    __shared__ float lt[4];
    __shared__ unsigned lc[4];

    // ---- XCD-chunked bijective swizzle (2080 = 8 * 260) ----
    const int bid0 = blockIdx.x;
    const int bid  = (bid0 & 7) * 260 + (bid0 >> 3);

    // ---- triangular pair decode: bid -> (bi, bj), bi<=bj, 64 tiles/dim ----
    int r = (int)((129.0f - sqrtf(16641.0f - 8.0f * (float)bid)) * 0.5f);
    while (64 * r - (r * (r - 1)) / 2 > bid) --r;
    while (64 * (r + 1) - ((r + 1) * r) / 2 <= bid) ++r;
    const int bi = r;
    const int bj = bi + (bid - (64 * r - (r * (r - 1)) / 2));
    const bool diag = (bi == bj);
    const int i0 = bi << 6;
    const int j0 = bj << 6;

    const int tid  = threadIdx.x;
    const int w    = tid >> 6;
    const int lane = tid & 63;
    const int l15  = lane & 15;
    const int l4   = lane >> 4;
    const int wr   = w >> 1;      // 0..1
    const int wc   = w & 1;       // 0..1

    // ---- epilogue scalar preload (n1, n2, dpos per side) ----
    if (tid < 128) {
        const int side = tid >> 6;               // 0: i-side, 1: j-side
        const int t = tid & 63;
        const int g = (side ? j0 : i0) + t;
        float* s = sc + side * 192;
        s[t] = n1[g]; s[64 + t] = n2[g]; s[128 + t] = dpos[g];
    }

    // ---- per-lane fragment pointers (k enters as +64B imm per step) ----
    const char* e1c = (const char*)e1b;
    const char* e2c = (const char*)e2b;
    const int koff = l4 << 4;                    // l4 * 16 bytes
    const char* pa1[2]; const char* pa2[2];
    const char* pb1[2]; const char* pb2[2];
    #pragma unroll
    for (int m = 0; m < 2; ++m) {
        const long ar = (long)(i0 + (wr << 5) + (m << 4) + l15) * 1024 + koff;
        pa1[m] = e1c + ar;  pa2[m] = e2c + ar;
        const long br = (long)(j0 + (wc << 5) + (m << 4) + l15) * 1024 + koff;
        pb1[m] = e1c + br;  pb2[m] = e2c + br;
    }

    fv4 acc11[2][2], acc22[2][2], acc12[2][2], accT[2][2];
    #pragma unroll
    for (int m = 0; m < 2; ++m)
        #pragma unroll
        for (int n = 0; n < 2; ++n) {
            acc11[m][n] = (fv4)0.0f;
            acc22[m][n] = (fv4)0.0f;
            acc12[m][n] = (fv4)0.0f;
            accT[m][n]  = (fv4)0.0f;
        }

    // ---- K-loop: 16 steps of K=32; no barriers, no LDS, imm k-offsets ----
    #pragma unroll
    for (int t = 0; t < 16; ++t) {
        const int kb = t << 6;                   // 0..960 bytes (13-bit imm)
        sv8 a1[2], a2[2], b1[2], b2[2];
        #pragma unroll
        for (int m = 0; m < 2; ++m) {
            a1[m] = *(const sv8*)(pa1[m] + kb);
            a2[m] = *(const sv8*)(pa2[m] + kb);
            b1[m] = *(const sv8*)(pb1[m] + kb);
            b2[m] = *(const sv8*)(pb2[m] + kb);
        }
        __builtin_amdgcn_s_setprio(1);
        #pragma unroll
        for (int m = 0; m < 2; ++m)
            #pragma unroll
            for (int n = 0; n < 2; ++n) {
                acc11[m][n] = __builtin_amdgcn_mfma_f32_16x16x32_bf16(a1[m], b1[n], acc11[m][n], 0, 0, 0);
                acc22[m][n] = __builtin_amdgcn_mfma_f32_16x16x32_bf16(a2[m], b2[n], acc22[m][n], 0, 0, 0);
                acc12[m][n] = __builtin_amdgcn_mfma_f32_16x16x32_bf16(a1[m], b2[n], acc12[m][n], 0, 0, 0);
            }
        if (!diag) {
            #pragma unroll
            for (int n = 0; n < 2; ++n)
                #pragma unroll
                for (int m = 0; m < 2; ++m)
                    accT[n][m] = __builtin_amdgcn_mfma_f32_16x16x32_bf16(b1[n], a2[m], accT[n][m], 0, 0, 0);
        }
        __builtin_amdgcn_s_setprio(0);
    }

    __syncthreads();   // scalar LDS writes visible for epilogue

    // ---- fused epilogue (sqrt-domain, R2/R4-proven) ----
    float    ltot = 0.0f;
    unsigned lcnt = 0;
    const bool bt = !diag;
    const float* scI = sc;
    const float* scJ = sc + 192;

    float n1c[2], n2c[2], dpc[2], mdpc[2];
    #pragma unroll
    for (int n = 0; n < 2; ++n) {
        const int cl = (wc << 5) + (n << 4) + l15;
        n1c[n] = scJ[cl]; n2c[n] = scJ[64 + cl];
        dpc[n] = scJ[128 + cl]; mdpc[n] = dpc[n] + MARGIN_F;
    }
    float n2ic[2], dpic[2], mdpic[2];
    #pragma unroll
    for (int m = 0; m < 2; ++m) {
        const int il = (wr << 5) + (m << 4) + l15;
        n2ic[m] = scI[64 + il]; dpic[m] = scI[128 + il]; mdpic[m] = dpic[m] + MARGIN_F;
    }

    #pragma unroll
    for (int m = 0; m < 2; ++m) {
        #pragma unroll
        for (int rr = 0; rr < 4; ++rr) {
            const int rl  = (wr << 5) + (m << 4) + (l4 << 2) + rr;
            const int row = i0 + rl;
            const float n1r = scI[rl], n2r = scI[64 + rl];
            const float dpr = scI[128 + rl], mdpr = dpr + MARGIN_F;
            #pragma unroll
            for (int n = 0; n < 2; ++n) {
                const int cc = j0 + (wc << 5) + (n << 4) + l15;
                const bool off = bt || (row != cc);
                bool c;

                float s11 = sqrtf(fmaxf(fmaf(-2.0f, acc11[m][n][rr], n1r + n1c[n]), 0.0f));
                c = off && (dpr    < s11); lcnt += c; ltot += c ? fmaxf(mdpr    - s11, 0.0f) : 0.0f;
                c = bt  && (dpc[n] < s11); lcnt += c; ltot += c ? fmaxf(mdpc[n] - s11, 0.0f) : 0.0f;

                float s22 = sqrtf(fmaxf(fmaf(-2.0f, acc22[m][n][rr], n2r + n2c[n]), 0.0f));
                c = off && (dpr    < s22); lcnt += c; ltot += c ? fmaxf(mdpr    - s22, 0.0f) : 0.0f;
                c = bt  && (dpc[n] < s22); lcnt += c; ltot += c ? fmaxf(mdpc[n] - s22, 0.0f) : 0.0f;

                float s12 = sqrtf(fmaxf(fmaf(-2.0f, acc12[m][n][rr], n1r + n2c[n]), 0.0f));
                c = off && (dpr    < s12); lcnt += c; ltot += c ? fmaxf(mdpr    - s12, 0.0f) : 0.0f;
                c = off && (dpc[n] < s12); lcnt += c; ltot += c ? fmaxf(mdpc[n] - s12, 0.0f) : 0.0f;
            }
        }
    }

    if (bt) {
        #pragma unroll
        for (int n = 0; n < 2; ++n) {
            #pragma unroll
            for (int rr = 0; rr < 4; ++rr) {
                const int jl = (wc << 5) + (n << 4) + (l4 << 2) + rr;
                const float n1jr = scJ[jl], dpjr = scJ[128 + jl], mdpjr = dpjr + MARGIN_F;
                #pragma unroll
                for (int m = 0; m < 2; ++m) {
                    float s = sqrtf(fmaxf(fmaf(-2.0f, accT[n][m][rr], n1jr + n2ic[m]), 0.0f));
                    bool c;
                    c = dpjr    < s; lcnt += c; ltot += c ? fmaxf(mdpjr    - s, 0.0f) : 0.0f;
                    c = dpic[m] < s; lcnt += c; ltot += c ? fmaxf(mdpic[m] - s, 0.0f) : 0.0f;
                }
            }
        }
    }

    // ---- block reduction: wave shuffle -> LDS -> one atomic pair ----
    #pragma unroll
    for (int o = 32; o; o >>= 1) {
        ltot += __shfl_down(ltot, o);
        lcnt += __shfl_down(lcnt, o);
    }
    if (lane == 0) { lt[w] = ltot; lc[w] = lcnt; }
    __syncthreads();
    if (tid == 0) {
        float T = 0.0f; unsigned C = 0;
        #pragma unroll
        for (int x = 0; x < 4; ++x) { T += lt[x]; C += lc[x]; }
        atomicAdd(total, T);
        atomicAdd(count, C);
    }
}

__global__ void finalize_kernel(const float* __restrict__ total,
                                const unsigned* __restrict__ count,
                                float* __restrict__ out)
{
    out[0] = total[0] / fmaxf((float)count[0], 1.0f);
}

// =====================================================================
// Workspace layout (~8.6 MB):
//   [0,8)        : total (f32), count (u32)
//   [1024, ...)  : n1[4096], n2[4096], dpos[4096]  (f32)
//   [131072, ..) : e1b 4096x512 bf16 (4MB), then e2b (4MB)
// =====================================================================
extern "C" void kernel_launch(void* const* d_in, const int* in_sizes, int n_in,
                              void* d_out, int out_size, void* d_ws, size_t ws_size,
                              hipStream_t stream) {
    const float* e1 = (const float*)d_in[0];
    const float* e2 = (const float*)d_in[1];
    char* ws = (char*)d_ws;

    float*    total = (float*)ws;
    unsigned* count = (unsigned*)(ws + 4);
    float* n1   = (float*)(ws + 1024);
    float* n2   = n1 + 4096;
    float* dpos = n2 + 4096;
    unsigned short* e1b = (unsigned short*)(ws + (1 << 17));
    unsigned short* e2b = e1b + (size_t)4096 * 512;

    hipMemsetAsync(ws, 0, 64, stream);
    prep_kernel<<<4096, 128, 0, stream>>>(e1, e2, e1b, e2b, n1, n2, dpos);
    triplet_main<<<2080, 256, 0, stream>>>(e1b, e2b, n1, n2, dpos, total, count);
    finalize_kernel<<<1, 1, 0, stream>>>(total, count, (float*)d_out);
}

// Round 8
// 99.026 us; speedup vs baseline: 1.6086x; 1.6086x over previous
//
#include <hip/hip_runtime.h>
#include <cstdint>

#define MARGIN_F 0.2f

typedef __attribute__((ext_vector_type(8))) short sv8;   // 8 x bf16 (4 VGPRs)
typedef __attribute__((ext_vector_type(4))) float fv4;   // MFMA accumulator

// ---- round-to-nearest-even fp32 -> bf16 (bit pattern) ----
__device__ __forceinline__ unsigned short f2bf(float x) {
    unsigned u = __float_as_uint(x);
    unsigned r = (u + 0x7fffu + ((u >> 16) & 1u)) >> 16;
    return (unsigned short)r;
}

// ---- async global->LDS, 16B per lane (dest = wave-uniform base + lane*16) ----
__device__ __forceinline__ void gload16(const void* g, void* l) {
    __builtin_amdgcn_global_load_lds(
        (const __attribute__((address_space(1))) unsigned*)g,
        (__attribute__((address_space(3))) unsigned*)l,
        16, 0, 0);
}

// =====================================================================
// prep: norms, d_pos (fp32 exact) + bf16 conversion of e1,e2
// =====================================================================
__global__ __launch_bounds__(128) void prep_kernel(
    const float* __restrict__ e1, const float* __restrict__ e2,
    unsigned short* __restrict__ e1b, unsigned short* __restrict__ e2b,
    float* __restrict__ n1, float* __restrict__ n2, float* __restrict__ dpos)
{
    const int row = blockIdx.x;
    const int t = threadIdx.x;
    const float4 a = reinterpret_cast<const float4*>(e1 + (size_t)row * 512)[t];
    const float4 b = reinterpret_cast<const float4*>(e2 + (size_t)row * 512)[t];

    ushort4 pa, pb;
    pa.x = f2bf(a.x); pa.y = f2bf(a.y); pa.z = f2bf(a.z); pa.w = f2bf(a.w);
    pb.x = f2bf(b.x); pb.y = f2bf(b.y); pb.z = f2bf(b.z); pb.w = f2bf(b.w);
    reinterpret_cast<ushort4*>(e1b + (size_t)row * 512)[t] = pa;
    reinterpret_cast<ushort4*>(e2b + (size_t)row * 512)[t] = pb;

    float s1 = a.x*a.x + a.y*a.y + a.z*a.z + a.w*a.w;
    float s2 = b.x*b.x + b.y*b.y + b.z*b.z + b.w*b.w;
    float dx = a.x-b.x, dy = a.y-b.y, dz = a.z-b.z, dw = a.w-b.w;
    float sp = dx*dx + dy*dy + dz*dz + dw*dw;

    #pragma unroll
    for (int o = 32; o; o >>= 1) {
        s1 += __shfl_down(s1, o);
        s2 += __shfl_down(s2, o);
        sp += __shfl_down(sp, o);
    }
    __shared__ float r1[2], r2[2], rp[2];
    if ((t & 63) == 0) { int wv = t >> 6; r1[wv] = s1; r2[wv] = s2; rp[wv] = sp; }
    __syncthreads();
    if (t == 0) {
        n1[row] = r1[0] + r1[1];
        n2[row] = r2[0] + r2[1];
        dpos[row] = sqrtf(rp[0] + rp[1]);
    }
}

// =====================================================================
// main: m97-faithful schedule on flavor-decomposed 128x128 gram tiles.
//   bid <  1024 : G12 = e1 . e2^T, FULL 32x32 grid (D12 row + D21 col)
//   bid <  1552 : G11 = e1 . e1^T, triangle bi<=bj (row + sym col terms)
//   bid >= 1552 : G22 = e2 . e2^T, triangle
// Schedule: single 32KB LDS buffer, stage -> __syncthreads -> compute ->
// __syncthreads (the proven 874-TF m97 loop; no dbuf, no asm, no setprio).
// grid: 2080 blocks x 256 threads (4 waves 2x2; wave region 64x64).
// =====================================================================
__global__ __launch_bounds__(256, 3) void triplet_main(
    const unsigned short* __restrict__ e1b, const unsigned short* __restrict__ e2b,
    const float* __restrict__ n1, const float* __restrict__ n2,
    const float* __restrict__ dpos,
    float* __restrict__ total, unsigned* __restrict__ count)
{
    __shared__ char buf[32768];        // A tile [0,16K) | B tile [16K,32K)
    __shared__ float scRN[128], scRD[128], scCN[128], scCD[128];
    __shared__ float lt[4];
    __shared__ unsigned lc[4];

    // ---- XCD-chunked bijective swizzle (2080 = 8 * 260) ----
    const int bid0 = blockIdx.x;
    const int bid  = (bid0 & 7) * 260 + (bid0 >> 3);

    // ---- flavor decode ----
    int bi, bj, flavor;                 // 0=G12 1=G11 2=G22
    if (bid < 1024) { flavor = 0; bi = bid >> 5; bj = bid & 31; }
    else {
        int b = bid - 1024; flavor = 1;
        if (b >= 528) { b -= 528; flavor = 2; }
        int r = (int)((65.0f - sqrtf(4225.0f - 8.0f * (float)b)) * 0.5f);
        while (32 * r - (r * (r - 1)) / 2 > b) --r;
        while (32 * (r + 1) - ((r + 1) * r) / 2 <= b) ++r;
        bi = r; bj = r + (b - (32 * r - (r * (r - 1)) / 2));
    }
    const int i0 = bi << 7, j0 = bj << 7;
    const char* Xc = (const char*)((flavor == 2) ? e2b : e1b);   // i-side rows
    const char* Yc = (const char*)((flavor == 1) ? e1b : e2b);   // j-side rows
    const float* nR = (flavor == 2) ? n2 : n1;
    const float* nC = (flavor == 1) ? n1 : n2;
    const bool emitCol = (flavor == 0) || (i0 != j0);
    const bool needNeq = (i0 == j0);

    const int tid  = threadIdx.x;
    const int w    = tid >> 6;
    const int lane = tid & 63;
    const int l15  = lane & 15;
    const int l4   = lane >> 4;
    const int wr   = w >> 1;      // 0..1
    const int wc   = w & 1;       // 0..1

    // ---- epilogue scalar preload (n-side, dpos per side) ----
    if (tid < 128)      { scRN[tid] = nR[i0 + tid]; scRD[tid] = dpos[i0 + tid]; }
    else { const int t = tid - 128; scCN[t] = nC[j0 + t]; scCD[t] = dpos[j0 + t]; }

    // ---- loop-invariant staging addresses (k enters as +128B/step) ----
    // chunk c: 0..3 -> A tile, 4..7 -> B tile; 8 gload16/thread/step (32KB)
    long srcA[4], srcB[4];
    #pragma unroll
    for (int c = 0; c < 4; ++c) {
        const int chA = tid + (c << 8);              // 0..1023
        const int rA  = chA >> 3;                    // 0..127
        srcA[c] = (long)(i0 + rA) * 1024 + (((chA & 7) << 4) ^ ((rA & 7) << 4));
        srcB[c] = (long)(j0 + rA) * 1024 + (((chA & 7) << 4) ^ ((rA & 7) << 4));
    }
    const char* baseA = Xc;
    const char* baseB = Yc;
    const int ldst = w << 10;                        // wave-uniform dest part

    // ---- loop-invariant swizzled ds_read bases; m/n step +2048, khalf ^64 --
    const int slot = (l4 << 4) ^ ((l15 & 7) << 4);
    const int aB = ((wr << 6) + l15) * 128 + slot;
    const int bB = 16384 + ((wc << 6) + l15) * 128 + slot;

    fv4 acc[4][4];
    #pragma unroll
    for (int m = 0; m < 4; ++m)
        #pragma unroll
        for (int n = 0; n < 4; ++n) acc[m][n] = (fv4)0.0f;

    // ---- m97 loop: stage -> sync -> compute(2 k-halves) -> sync ----
    for (int t = 0; t < 8; ++t) {
        const long kb = (long)t << 7;
        #pragma unroll
        for (int c = 0; c < 4; ++c) {
            gload16(baseA + srcA[c] + kb, buf + (c << 12) + ldst);
            gload16(baseB + srcB[c] + kb, buf + 16384 + (c << 12) + ldst);
        }
        __syncthreads();
        #pragma unroll
        for (int h = 0; h < 2; ++h) {
            const int H = h << 6;                    // ^0 / ^64
            sv8 a_[4], b_[4];
            #pragma unroll
            for (int m = 0; m < 4; ++m)
                a_[m] = *(const sv8*)(buf + ((aB + m * 2048) ^ H));
            #pragma unroll
            for (int n = 0; n < 4; ++n)
                b_[n] = *(const sv8*)(buf + ((bB + n * 2048) ^ H));
            #pragma unroll
            for (int m = 0; m < 4; ++m)
                #pragma unroll
                for (int n = 0; n < 4; ++n)
                    acc[m][n] = __builtin_amdgcn_mfma_f32_16x16x32_bf16(
                        a_[m], b_[n], acc[m][n], 0, 0, 0);
        }
        __syncthreads();
    }

    // ---- fused epilogue (sqrt-domain): C/D col=lane&15, row=(lane>>4)*4+rr --
    float    ltot = 0.0f;
    unsigned lcnt = 0;

    float cN_[4], cD_[4], cM_[4];
    #pragma unroll
    for (int n = 0; n < 4; ++n) {
        const int cl = (wc << 6) + (n << 4) + l15;
        cN_[n] = scCN[cl]; cD_[n] = scCD[cl]; cM_[n] = cD_[n] + MARGIN_F;
    }

    #pragma unroll
    for (int m = 0; m < 4; ++m) {
        #pragma unroll
        for (int rr = 0; rr < 4; ++rr) {
            const int rl = (wr << 6) + (m << 4) + (l4 << 2) + rr;
            const float rN = scRN[rl], rD = scRD[rl], rM = rD + MARGIN_F;
            #pragma unroll
            for (int n = 0; n < 4; ++n) {
                const int cl = (wc << 6) + (n << 4) + l15;
                const float s = sqrtf(fmaxf(fmaf(-2.0f, acc[m][n][rr], rN + cN_[n]), 0.0f));
                const bool neq = (!needNeq) || (rl != cl);
                bool c1 = neq && (rD < s);
                lcnt += c1; ltot += c1 ? fmaxf(rM - s, 0.0f) : 0.0f;
                bool c2 = emitCol && neq && (cD_[n] < s);
                lcnt += c2; ltot += c2 ? fmaxf(cM_[n] - s, 0.0f) : 0.0f;
            }
        }
    }

    // ---- block reduction: wave shuffle -> LDS -> one atomic pair ----
    #pragma unroll
    for (int o = 32; o; o >>= 1) {
        ltot += __shfl_down(ltot, o);
        lcnt += __shfl_down(lcnt, o);
    }
    if (lane == 0) { lt[w] = ltot; lc[w] = lcnt; }
    __syncthreads();
    if (tid == 0) {
        float T = 0.0f; unsigned C = 0;
        #pragma unroll
        for (int x = 0; x < 4; ++x) { T += lt[x]; C += lc[x]; }
        atomicAdd(total, T);
        atomicAdd(count, C);
    }
}

__global__ void finalize_kernel(const float* __restrict__ total,
                                const unsigned* __restrict__ count,
                                float* __restrict__ out)
{
    out[0] = total[0] / fmaxf((float)count[0], 1.0f);
}

// =====================================================================
// Workspace layout (~8.6 MB):
//   [0,8)        : total (f32), count (u32)
//   [1024, ...)  : n1[4096], n2[4096], dpos[4096]  (f32)
//   [131072, ..) : e1b 4096x512 bf16 (4MB), then e2b (4MB)
// =====================================================================
extern "C" void kernel_launch(void* const* d_in, const int* in_sizes, int n_in,
                              void* d_out, int out_size, void* d_ws, size_t ws_size,
                              hipStream_t stream) {
    const float* e1 = (const float*)d_in[0];
    const float* e2 = (const float*)d_in[1];
    char* ws = (char*)d_ws;

    float*    total = (float*)ws;
    unsigned* count = (unsigned*)(ws + 4);
    float* n1   = (float*)(ws + 1024);
    float* n2   = n1 + 4096;
    float* dpos = n2 + 4096;
    unsigned short* e1b = (unsigned short*)(ws + (1 << 17));
    unsigned short* e2b = e1b + (size_t)4096 * 512;

    hipMemsetAsync(ws, 0, 64, stream);
    prep_kernel<<<4096, 128, 0, stream>>>(e1, e2, e1b, e2b, n1, n2, dpos);
    triplet_main<<<2080, 256, 0, stream>>>(e1b, e2b, n1, n2, dpos, total, count);
    finalize_kernel<<<1, 1, 0, stream>>>(total, count, (float*)d_out);
}